// Round 2
// baseline (501.202 us; speedup 1.0000x reference)
//
#include <hip/hip_runtime.h>
#include <hip/hip_cooperative_groups.h>

namespace cg = cooperative_groups;

typedef float f32x4  __attribute__((ext_vector_type(4)));
typedef float f32x16 __attribute__((ext_vector_type(16)));
typedef short s16x8  __attribute__((ext_vector_type(8)));

constexpr int NL  = 31;
constexpr int BB  = 64;
constexpr int TT  = 512;
constexpr int DD  = 768;
constexpr int RTOT = BB * TT;
constexpr int IDX_EOS = 29;
constexpr int IDX_BOS = 30;
constexpr float LOG2E = 1.4426950408889634f;
constexpr float LN2F  = 0.6931471805599453f;

union Frag8 { unsigned u[4]; s16x8 s; };

__device__ inline unsigned pk2(float a, float b) {
  unsigned ua = __float_as_uint(a), ub = __float_as_uint(b);
  ua = (ua + 0x7fffu + ((ua >> 16) & 1u)) >> 16;   // RNE f32->bf16
  ub = (ub + 0x7fffu + ((ub >> 16) & 1u)) >> 16;
  return ua | (ub << 16);
}
__device__ inline unsigned short bf16r(float a) {
  unsigned ua = __float_as_uint(a);
  return (unsigned short)((ua + 0x7fffu + ((ua >> 16) & 1u)) >> 16);
}

__device__ inline float bfly_max32(float v) {
#define STEPM(K) { float o = __int_as_float(__builtin_amdgcn_ds_swizzle(__float_as_int(v), ((K) << 10) | 0x1f)); v = fmaxf(v, o); }
  STEPM(1) STEPM(2) STEPM(4) STEPM(8) STEPM(16)
#undef STEPM
  return v;
}
__device__ inline float bfly_sum32(float v) {
#define STEPS(K) { float o = __int_as_float(__builtin_amdgcn_ds_swizzle(__float_as_int(v), ((K) << 10) | 0x1f)); v = v + o; }
  STEPS(1) STEPS(2) STEPS(4) STEPS(8) STEPS(16)
#undef STEPS
  return v;
}

// D(C-layout, f32[16]) -> B-frag(bf16) half-swap repack [R2-verified]
__device__ inline void repack(const float E[16], int h, Frag8& B1, Frag8& B2) {
  unsigned o1a = pk2(E[4 * h], E[4 * h + 1]), o1b = pk2(E[4 * h + 2], E[4 * h + 3]);
  unsigned o2a = pk2(E[8 + 4 * h], E[8 + 4 * h + 1]), o2b = pk2(E[8 + 4 * h + 2], E[8 + 4 * h + 3]);
  int hb = 4 * (1 - h);
  unsigned s1a = pk2(E[hb], E[hb + 1]),         s1b = pk2(E[hb + 2], E[hb + 3]);
  unsigned s2a = pk2(E[8 + hb], E[8 + hb + 1]), s2b = pk2(E[8 + hb + 2], E[8 + hb + 3]);
  unsigned r1a = __shfl_xor((int)s1a, 32), r1b = __shfl_xor((int)s1b, 32);
  unsigned r2a = __shfl_xor((int)s2a, 32), r2b = __shfl_xor((int)s2b, 32);
  if (h == 0) {
    B1.u[0] = o1a; B1.u[1] = o1b; B1.u[2] = r1a; B1.u[3] = r1b;
    B2.u[0] = o2a; B2.u[1] = o2b; B2.u[2] = r2a; B2.u[3] = r2b;
  } else {
    B1.u[0] = r1a; B1.u[1] = r1b; B1.u[2] = o1a; B1.u[3] = o1b;
    B2.u[0] = r2a; B2.u[1] = r2b; B2.u[2] = o2a; B2.u[3] = o2b;
  }
}

__device__ inline void renorm16(float E[16], float& Sacc) {
  float m = E[0];
#pragma unroll
  for (int r = 1; r < 16; ++r) m = fmaxf(m, E[r]);
  m = bfly_max32(m);
  m = fmaxf(m, __shfl_xor(m, 32));
  float lg = truncf(log2f(m));
  Sacc += lg;
  float sc = exp2f(-lg);
#pragma unroll
  for (int r = 0; r < 16; ++r) E[r] *= sc;
}

// bf16 row-major 32x32 matrix -> A-frags (A[m][k], m = lane&31)
__device__ inline void load_A16(const unsigned short* M, int l, int h, Frag8& A1, Frag8& A2) {
  A1.s = *(const s16x8*)(M + l * 32 + 8 * h);
  A2.s = *(const s16x8*)(M + l * 32 + 16 + 8 * h);
}
// bf16 row-major 32x32 matrix -> B-frags (B[k][n], n = lane&31)
__device__ inline void load_B16(const unsigned short* M, int l, int h, Frag8& B1, Frag8& B2) {
#pragma unroll
  for (int m = 0; m < 4; ++m) {
    int k = 8 * h + 2 * m;
    unsigned lo0 = M[k * 32 + l],        hi0 = M[(k + 1) * 32 + l];
    unsigned lo1 = M[(k + 16) * 32 + l], hi1 = M[(k + 17) * 32 + l];
    B1.u[m] = lo0 | (hi0 << 16);
    B2.u[m] = lo1 | (hi1 << 16);
  }
}

// LDS tree node: result = T[ja] * T[jb] -> stored at T[jb] (bf16), Ts[jb] += S
__device__ inline void tree_node(unsigned short* Tb, float* Ts, int ja, int jb, int l, int h) {
  Frag8 A1, A2, B1, B2;
  load_A16(Tb + ja * 1024, l, h, A1, A2);
  load_B16(Tb + jb * 1024, l, h, B1, B2);
  f32x16 D = {};
  D = __builtin_amdgcn_mfma_f32_32x32x16_bf16(A1.s, B1.s, D, 0, 0, 0);
  D = __builtin_amdgcn_mfma_f32_32x32x16_bf16(A2.s, B2.s, D, 0, 0, 0);
  float E[16];
#pragma unroll
  for (int r = 0; r < 16; ++r) E[r] = D[r];
  float S = Ts[ja] + Ts[jb];
  renorm16(E, S);
#pragma unroll
  for (int r = 0; r < 16; ++r) {
    int row = (r & 3) + 8 * (r >> 2) + 4 * h;
    Tb[jb * 1024 + row * 32 + l] = bf16r(E[r]);
  }
  if (l == 0 && h == 0) Ts[jb] = S;
}

// ------------- K0: state_w -> bf16 padded ----------------------------------
__global__ void k_prep(const float* __restrict__ sw, unsigned short* __restrict__ Bw) {
  for (int i = blockIdx.x * 256 + threadIdx.x; i < 32 * DD; i += 8 * 256)
    Bw[i] = (i < NL * DD) ? bf16r(sw[i]) : (unsigned short)0;
}

// ------------- Fused cooperative kernel: all phases -------------------------
// grid = 512 blocks x 256 thr (2 blocks/CU co-resident). Phases separated by
// grid.sync():
//  P1: out_s GEMM + energy stream + tgt-energy partial (block b -> rows b*64..)
//  P2: 8 seg units/block + 2 quad products in LDS (Mseg never goes global)
//  P3: blocks 0..63: per-batch pairwise tree product (depth 5) + loss
__global__ __launch_bounds__(256, 2) void k_fused(
    const float* __restrict__ inp, const unsigned short* __restrict__ Bw,
    const float* __restrict__ sb, const float* __restrict__ msk,
    const float* __restrict__ trans, const int* __restrict__ target,
    float* __restrict__ outs, float* __restrict__ energy,
    float* __restrict__ ws_partial, unsigned short* __restrict__ Mq16,
    float* __restrict__ Sq, float* __restrict__ loss)
{
  __shared__ __align__(16) union {
    struct { unsigned short As[4][16 * 72]; float tr[961]; float osh[64 * NL]; } p1;
    struct { float ub[4][256]; unsigned short Ms[2][4][1024]; float Ss[2][4]; } p2;
    struct { unsigned short T[16][1024]; float Ts[16]; } p3;
  } sm;

  cg::grid_group grid = cg::this_grid();
  int tid = threadIdx.x, wave = tid >> 6, lane = tid & 63;

  // ===================== Phase 1: GEMM + energy ============================
  {
    int quad = lane >> 4, l15 = lane & 15;
    int r0 = blockIdx.x * 64;
    int rw = r0 + wave * 16;

    for (int idx = tid; idx < 961; idx += 256) sm.p1.tr[idx] = trans[idx];

    int srow = lane >> 2, scol = lane & 3;      // staging: 4 lanes per row
    const float* gsrc = inp + (size_t)(rw + srow) * DD + scol * 4;
    unsigned short* asb = sm.p1.As[wave];
    unsigned* dw = (unsigned*)asb;
    int wbase = srow * 36 + scol * 2;

    f32x4 pre[4];
#pragma unroll
    for (int i = 0; i < 4; ++i) pre[i] = *(const f32x4*)(gsrc + i * 16);

    f32x4 acc[2] = {};
    for (int kc = 0; kc < 12; ++kc) {
#pragma unroll
      for (int i = 0; i < 4; ++i) {
        dw[wbase + i * 8]     = pk2(pre[i][0], pre[i][1]);
        dw[wbase + i * 8 + 1] = pk2(pre[i][2], pre[i][3]);
      }
      if (kc < 11) {
        const float* g2 = gsrc + (kc + 1) * 64;
#pragma unroll
        for (int i = 0; i < 4; ++i) pre[i] = *(const f32x4*)(g2 + i * 16);
      }
#pragma unroll
      for (int ks = 0; ks < 2; ++ks) {
        s16x8 af = *(const s16x8*)(asb + l15 * 72 + ks * 32 + quad * 8);
#pragma unroll
        for (int ct = 0; ct < 2; ++ct) {
          s16x8 bf = *(const s16x8*)(Bw + (ct * 16 + l15) * DD + kc * 64 + ks * 32 + quad * 8);
          acc[ct] = __builtin_amdgcn_mfma_f32_16x16x32_bf16(af, bf, acc[ct], 0, 0, 0);
        }
      }
    }
    // epilogue: bias + mask, park tile in LDS + global outs
#pragma unroll
    for (int ct = 0; ct < 2; ++ct) {
      int n = ct * 16 + l15;
      if (n >= NL) continue;
      float b = sb[n];
#pragma unroll
      for (int r = 0; r < 4; ++r) {
        int lr = wave * 16 + quad * 4 + r;
        int row = r0 + lr;
        float v = acc[ct][r] + b;
        if (n == IDX_EOS && msk[row] == 0.f) v += 20000.f;
        sm.p1.osh[lr * NL + n] = v;
        outs[(size_t)row * NL + n] = v;
      }
    }
    __syncthreads();

    // tgt-energy partial for this block's 64 rows
    if (tid < 64) {
      int r = r0 + tid;
      int tg = target[r];
      int prv = ((r & (TT - 1)) == 0) ? IDX_BOS : target[r - 1];
      float cc = sm.p1.tr[prv * NL + tg] + sm.p1.osh[tid * NL + tg];
#pragma unroll
      for (int off = 32; off; off >>= 1) cc += __shfl_down(cc, off);
      if (tid == 0) ws_partial[blockIdx.x] = cc;
    }

    // energy: 64*961 = 61504 f32 = 15376 vec4 (base 16B-aligned)
    float* dst = energy + (size_t)r0 * 961;
#pragma unroll 4
    for (int it = 0; it < 60; ++it) {
      int v = it * 256 + tid;
      int e = v * 4;
      f32x4 val;
#pragma unroll
      for (int k = 0; k < 4; ++k) {
        unsigned x = e + k;
        unsigned q = __umulhi(x, 4469269u);        // x / 961 (exact, x < 20M)
        unsigned c = x - q * 961u;
        unsigned j = c - 31u * ((c * 67651u) >> 21); // c % 31 (exact, c < 961)
        val[k] = sm.p1.tr[c] + sm.p1.osh[q * NL + j];
      }
      *(f32x4*)(dst + e) = val;
    }
    if (tid < 16) {
      int e = (15360 + tid) * 4;
      f32x4 val;
#pragma unroll
      for (int k = 0; k < 4; ++k) {
        unsigned x = e + k;
        unsigned q = __umulhi(x, 4469269u);
        unsigned c = x - q * 961u;
        unsigned j = c - 31u * ((c * 67651u) >> 21);
        val[k] = sm.p1.tr[c] + sm.p1.osh[q * NL + j];
      }
      *(f32x4*)(dst + e) = val;
    }
  }

  __threadfence();
  grid.sync();

  // ===================== Phase 2: seg units + quads ========================
  {
    int l = lane & 31, h = lane >> 5;

    // trans A-frags (constant across reps) + identity B template
    Frag8 At1, At2;
#pragma unroll
    for (int m = 0; m < 4; ++m) {
      int k0 = 8 * h + 2 * m, k1 = k0 + 1;
      float a0 = (k0 < NL && l < NL) ? exp2f(LOG2E * trans[k0 * NL + l]) : 0.f;
      float a1 = (k1 < NL && l < NL) ? exp2f(LOG2E * trans[k1 * NL + l]) : 0.f;
      At1.u[m] = pk2(a0, a1);
      int k2 = 16 + k0, k3 = 16 + k1;
      float a2 = (k2 < NL && l < NL) ? exp2f(LOG2E * trans[k2 * NL + l]) : 0.f;
      float a3 = (k3 < NL && l < NL) ? exp2f(LOG2E * trans[k3 * NL + l]) : 0.f;
      At2.u[m] = pk2(a2, a3);
    }

#pragma unroll
    for (int rep = 0; rep < 2; ++rep) {
      int unit = blockIdx.x * 8 + rep * 4 + wave;
      int b = unit >> 6, c = unit & 63;
      int t0 = 1 + c * 8;
      int n = (c == 63) ? 7 : 8;

      float* ub = sm.p2.ub[wave];
#pragma unroll
      for (int it = 0; it < 4; ++it) {
        int idx = lane + it * 64;
        int row = idx >> 5, col = idx & 31;
        float v = 0.f;
        if (col < NL && row < n)
          v = exp2f(LOG2E * outs[((size_t)b * TT + t0 + row) * NL + col]);
        ub[idx] = v;
      }

      Frag8 B1, B2;
#pragma unroll
      for (int m = 0; m < 4; ++m) {
        int k0 = 8 * h + 2 * m, k1 = k0 + 1;
        int k2 = 16 + k0, k3 = 16 + k1;
        B1.u[m] = ((k0 == l) ? 0x3f80u : 0u) | (((k1 == l) ? 0x3f80u : 0u) << 16);
        B2.u[m] = ((k2 == l) ? 0x3f80u : 0u) | (((k3 == l) ? 0x3f80u : 0u) << 16);
      }

      float E[16];
      for (int s = 0; s < n; ++s) {
        const float* us = ub + s * 32 + 4 * h;
        f32x4 u0 = *(const f32x4*)(us);
        f32x4 u1 = *(const f32x4*)(us + 8);
        f32x4 u2 = *(const f32x4*)(us + 16);
        f32x4 u3 = *(const f32x4*)(us + 24);
        f32x16 D = {};
        D = __builtin_amdgcn_mfma_f32_32x32x16_bf16(At1.s, B1.s, D, 0, 0, 0);
        D = __builtin_amdgcn_mfma_f32_32x32x16_bf16(At2.s, B2.s, D, 0, 0, 0);
#pragma unroll
        for (int jj = 0; jj < 4; ++jj) {
          E[jj]      = D[jj]      * u0[jj];
          E[4 + jj]  = D[4 + jj]  * u1[jj];
          E[8 + jj]  = D[8 + jj]  * u2[jj];
          E[12 + jj] = D[12 + jj] * u3[jj];
        }
        if (s + 1 < n) repack(E, h, B1, B2);
      }
      float S = 0.f;
      renorm16(E, S);
      unsigned short* mo = sm.p2.Ms[rep][wave];
#pragma unroll
      for (int r = 0; r < 16; ++r) {
        int row = (r & 3) + 8 * (r >> 2) + 4 * h;
        mo[row * 32 + l] = bf16r(E[r]);
      }
      if (lane == 0) sm.p2.Ss[rep][wave] = S;
    }
    __syncthreads();

    if (wave < 2) {
      // quad product Q = M3*M2*M1*M0, one wave per quad (waves 0,1)
      Frag8 A1, A2, B1, B2;
      load_B16(sm.p2.Ms[wave][0], l, h, B1, B2);
      float Sx = sm.p2.Ss[wave][0] + sm.p2.Ss[wave][1] + sm.p2.Ss[wave][2] + sm.p2.Ss[wave][3];
      float E2[16];
#pragma unroll
      for (int i = 1; i < 4; ++i) {
        load_A16(sm.p2.Ms[wave][i], l, h, A1, A2);
        f32x16 D = {};
        D = __builtin_amdgcn_mfma_f32_32x32x16_bf16(A1.s, B1.s, D, 0, 0, 0);
        D = __builtin_amdgcn_mfma_f32_32x32x16_bf16(A2.s, B2.s, D, 0, 0, 0);
#pragma unroll
        for (int r = 0; r < 16; ++r) E2[r] = D[r];
        if (i < 3) repack(E2, h, B1, B2);
      }
      renorm16(E2, Sx);
      int qg = blockIdx.x * 2 + wave;
      unsigned short* qo = Mq16 + (size_t)qg * 1024;
#pragma unroll
      for (int r = 0; r < 16; ++r) {
        int row = (r & 3) + 8 * (r >> 2) + 4 * h;
        qo[row * 32 + l] = bf16r(E2[r]);
      }
      if (lane == 0) Sq[qg] = Sx;
    }
  }

  __threadfence();
  grid.sync();

  // ===================== Phase 3: per-batch tree + loss ====================
  if (blockIdx.x < BB) {
    int bb = blockIdx.x;
    int l = lane & 31, h = lane >> 5;
    unsigned* Td = (unsigned*)sm.p3.T;
    const unsigned* src = (const unsigned*)(Mq16 + (size_t)bb * 16384);
    for (int idx = tid; idx < 8192; idx += 256) Td[idx] = src[idx];
    if (tid < 16) sm.p3.Ts[tid] = Sq[bb * 16 + tid];
    __syncthreads();

    unsigned short* T = sm.p3.T[0];
    float* Ts = sm.p3.Ts;

    // L1: 8 nodes (16->8): slot 2j <- T[2j+1]*T[2j]; wave w does j=w, j=w+4
    tree_node(T, Ts, 2 * wave + 1, 2 * wave, l, h);
    tree_node(T, Ts, 2 * (wave + 4) + 1, 2 * (wave + 4), l, h);
    __syncthreads();
    // L2: 4 nodes (8->4): slot 4j <- T[4j+2]*T[4j]; wave j
    tree_node(T, Ts, 4 * wave + 2, 4 * wave, l, h);
    __syncthreads();
    // L3: 2 nodes (4->2): slot 8j <- T[8j+4]*T[8j]; waves 0,1
    if (wave < 2) tree_node(T, Ts, 8 * wave + 4, 8 * wave, l, h);
    __syncthreads();
    // L4 + finalize (wave 0): full = T[8]*T[0]
    if (wave == 0) {
      Frag8 A1, A2, B1, B2;
      load_A16(T + 8 * 1024, l, h, A1, A2);
      load_B16(T, l, h, B1, B2);
      f32x16 D = {};
      D = __builtin_amdgcn_mfma_f32_32x32x16_bf16(A1.s, B1.s, D, 0, 0, 0);
      D = __builtin_amdgcn_mfma_f32_32x32x16_bf16(A2.s, B2.s, D, 0, 0, 0);
      float E[16];
#pragma unroll
      for (int r = 0; r < 16; ++r) E[r] = D[r];
      float S = Ts[0] + Ts[8];

      float p0 = (l < NL) ? exp2f(LOG2E * (trans[IDX_BOS * NL + l] + outs[(size_t)bb * TT * NL + l])) : 0.f;
      float sum_h = 0.f;
#pragma unroll
      for (int r = 0; r < 16; ++r) {
        float s = bfly_sum32(E[r] * p0);
        int row = (r & 3) + 8 * (r >> 2) + 4 * h;
        float We = (row < NL) ? exp2f(LOG2E * trans[row * NL + IDX_EOS]) : 0.f;
        sum_h += s * We;
      }
      float tot = sum_h + __shfl_xor(sum_h, 32);
      if (lane == 0) {
        float wst = 0.f;
#pragma unroll
        for (int i = 0; i < 8; ++i) wst += ws_partial[bb * 8 + i];
        loss[bb] = LN2F * (S + log2f(tot)) - wst;
      }
    }
  }
}

extern "C" void kernel_launch(void* const* d_in, const int* in_sizes, int n_in,
                              void* d_out, int out_size, void* d_ws, size_t ws_size,
                              hipStream_t stream) {
  const float* inp   = (const float*)d_in[0];   // (64,512,768) f32
  const int*   tgt   = (const int*)d_in[1];     // (64,512) int
  const float* msk   = (const float*)d_in[2];   // (64,512) f32
  const float* sw    = (const float*)d_in[3];   // (31,768) f32
  const float* sb    = (const float*)d_in[4];   // (31,) f32
  const float* trans = (const float*)d_in[5];   // (31,31) f32

  float* out    = (float*)d_out;
  float* loss   = out;
  float* energy = out + BB;

  // d_ws layout (~6.2 MB used)
  float* outs        = (float*)d_ws;                        // 32768*31 f32
  float* Sq          = outs + (size_t)RTOT * NL;            // 1024
  float* ws_partial  = Sq + 1024;                           // 512
  unsigned short* Mq16 = (unsigned short*)(ws_partial + 512); // 1024*1024 bf16
  unsigned short* Bw   = Mq16 + (size_t)1024 * 1024;          // 32*768 bf16

  k_prep<<<8, 256, 0, stream>>>(sw, Bw);

  const unsigned short* Bw_c = Bw;
  void* args[] = {
    (void*)&inp, (void*)&Bw_c, (void*)&sb, (void*)&msk, (void*)&trans, (void*)&tgt,
    (void*)&outs, (void*)&energy, (void*)&ws_partial, (void*)&Mq16, (void*)&Sq, (void*)&loss
  };
  hipLaunchCooperativeKernel((void*)k_fused, dim3(512), dim3(256), args, 0, stream);
}

// Round 3
// 311.530 us; speedup vs baseline: 1.6088x; 1.6088x over previous
//
#include <hip/hip_runtime.h>

typedef float f32x4  __attribute__((ext_vector_type(4)));
typedef float f32x16 __attribute__((ext_vector_type(16)));
typedef short s16x8  __attribute__((ext_vector_type(8)));

constexpr int NL  = 31;
constexpr int BB  = 64;
constexpr int TT  = 512;
constexpr int DD  = 768;
constexpr int RTOT = BB * TT;
constexpr int IDX_EOS = 29;
constexpr int IDX_BOS = 30;
constexpr float LOG2E = 1.4426950408889634f;
constexpr float LN2F  = 0.6931471805599453f;

union Frag8 { unsigned u[4]; s16x8 s; };

__device__ inline unsigned pk2(float a, float b) {
  unsigned ua = __float_as_uint(a), ub = __float_as_uint(b);
  ua = (ua + 0x7fffu + ((ua >> 16) & 1u)) >> 16;   // RNE f32->bf16
  ub = (ub + 0x7fffu + ((ub >> 16) & 1u)) >> 16;
  return ua | (ub << 16);
}
__device__ inline unsigned short bf16r(float a) {
  unsigned ua = __float_as_uint(a);
  return (unsigned short)((ua + 0x7fffu + ((ua >> 16) & 1u)) >> 16);
}

__device__ inline float bfly_max32(float v) {
#define STEPM(K) { float o = __int_as_float(__builtin_amdgcn_ds_swizzle(__float_as_int(v), ((K) << 10) | 0x1f)); v = fmaxf(v, o); }
  STEPM(1) STEPM(2) STEPM(4) STEPM(8) STEPM(16)
#undef STEPM
  return v;
}
__device__ inline float bfly_sum32(float v) {
#define STEPS(K) { float o = __int_as_float(__builtin_amdgcn_ds_swizzle(__float_as_int(v), ((K) << 10) | 0x1f)); v = v + o; }
  STEPS(1) STEPS(2) STEPS(4) STEPS(8) STEPS(16)
#undef STEPS
  return v;
}

// D(C-layout, f32[16]) -> B-frag(bf16) half-swap repack [R2-verified]
__device__ inline void repack(const float E[16], int h, Frag8& B1, Frag8& B2) {
  unsigned o1a = pk2(E[4 * h], E[4 * h + 1]), o1b = pk2(E[4 * h + 2], E[4 * h + 3]);
  unsigned o2a = pk2(E[8 + 4 * h], E[8 + 4 * h + 1]), o2b = pk2(E[8 + 4 * h + 2], E[8 + 4 * h + 3]);
  int hb = 4 * (1 - h);
  unsigned s1a = pk2(E[hb], E[hb + 1]),         s1b = pk2(E[hb + 2], E[hb + 3]);
  unsigned s2a = pk2(E[8 + hb], E[8 + hb + 1]), s2b = pk2(E[8 + hb + 2], E[8 + hb + 3]);
  unsigned r1a = __shfl_xor((int)s1a, 32), r1b = __shfl_xor((int)s1b, 32);
  unsigned r2a = __shfl_xor((int)s2a, 32), r2b = __shfl_xor((int)s2b, 32);
  if (h == 0) {
    B1.u[0] = o1a; B1.u[1] = o1b; B1.u[2] = r1a; B1.u[3] = r1b;
    B2.u[0] = o2a; B2.u[1] = o2b; B2.u[2] = r2a; B2.u[3] = r2b;
  } else {
    B1.u[0] = r1a; B1.u[1] = r1b; B1.u[2] = o1a; B1.u[3] = o1b;
    B2.u[0] = r2a; B2.u[1] = r2b; B2.u[2] = o2a; B2.u[3] = o2b;
  }
}

__device__ inline void renorm16(float E[16], float& Sacc) {
  float m = E[0];
#pragma unroll
  for (int r = 1; r < 16; ++r) m = fmaxf(m, E[r]);
  m = bfly_max32(m);
  m = fmaxf(m, __shfl_xor(m, 32));
  float lg = truncf(log2f(m));
  Sacc += lg;
  float sc = exp2f(-lg);
#pragma unroll
  for (int r = 0; r < 16; ++r) E[r] *= sc;
}

// bf16 row-major 32x32 matrix -> A-frags (A[m][k], m = lane&31)
__device__ inline void load_A16(const unsigned short* M, int l, int h, Frag8& A1, Frag8& A2) {
  A1.s = *(const s16x8*)(M + l * 32 + 8 * h);
  A2.s = *(const s16x8*)(M + l * 32 + 16 + 8 * h);
}
// bf16 row-major 32x32 matrix -> B-frags (B[k][n], n = lane&31)
__device__ inline void load_B16(const unsigned short* M, int l, int h, Frag8& B1, Frag8& B2) {
#pragma unroll
  for (int m = 0; m < 4; ++m) {
    int k = 8 * h + 2 * m;
    unsigned lo0 = M[k * 32 + l],        hi0 = M[(k + 1) * 32 + l];
    unsigned lo1 = M[(k + 16) * 32 + l], hi1 = M[(k + 17) * 32 + l];
    B1.u[m] = lo0 | (hi0 << 16);
    B2.u[m] = lo1 | (hi1 << 16);
  }
}

// ------------- K0: state_w -> bf16 padded ----------------------------------
__global__ void k_prep(const float* __restrict__ sw, unsigned short* __restrict__ Bw) {
  for (int i = blockIdx.x * 256 + threadIdx.x; i < 32 * DD; i += 8 * 256)
    Bw[i] = (i < NL * DD) ? bf16r(sw[i]) : (unsigned short)0;
}

// ------------- K1 fused: out_s GEMM + energy write + tgt-energy partial -----
// 2048 blocks x 16 rows each (8 blocks/CU, 32 waves/CU). Wave 0 does the
// 16-row GEMM (same per-wave code as before -> same MFMA capacity/CU), waves
// 1-3 preload trans to LDS; then all 4 waves stream the 16x961 energy tile.
// 4x the write-stream parallelism of the 512-block version.
__global__ __launch_bounds__(256) void k_outs(
    const float* __restrict__ inp, const unsigned short* __restrict__ Bw,
    const float* __restrict__ sb, const float* __restrict__ msk,
    const float* __restrict__ trans, const int* __restrict__ target,
    float* __restrict__ outs, float* __restrict__ energy,
    float* __restrict__ ws_partial)
{
  __shared__ __align__(16) unsigned short As[16 * 72];  // stride 72: 2-way banks (free)
  __shared__ float tr[961];
  __shared__ float osh[16 * NL];
  int tid = threadIdx.x, wave = tid >> 6, lane = tid & 63;
  int r0 = blockIdx.x * 16;

  if (wave) {
    // waves 1-3: trans -> LDS while wave 0 runs the GEMM
    for (int idx = tid - 64; idx < 961; idx += 192) tr[idx] = trans[idx];
  } else {
    int quad = lane >> 4, l15 = lane & 15;
    int srow = lane >> 2, scol = lane & 3;      // staging: 4 lanes per row
    const float* gsrc = inp + (size_t)(r0 + srow) * DD + scol * 4;
    unsigned* dw = (unsigned*)As;
    int wbase = srow * 36 + scol * 2;

    f32x4 pre[4];
#pragma unroll
    for (int i = 0; i < 4; ++i) pre[i] = *(const f32x4*)(gsrc + i * 16);

    f32x4 acc[2] = {};
    for (int kc = 0; kc < 12; ++kc) {
#pragma unroll
      for (int i = 0; i < 4; ++i) {
        dw[wbase + i * 8]     = pk2(pre[i][0], pre[i][1]);
        dw[wbase + i * 8 + 1] = pk2(pre[i][2], pre[i][3]);
      }
      if (kc < 11) {
        const float* g2 = gsrc + (kc + 1) * 64;
#pragma unroll
        for (int i = 0; i < 4; ++i) pre[i] = *(const f32x4*)(g2 + i * 16);
      }
#pragma unroll
      for (int ks = 0; ks < 2; ++ks) {
        s16x8 af = *(const s16x8*)((const unsigned short*)As + l15 * 72 + ks * 32 + quad * 8);
#pragma unroll
        for (int ct = 0; ct < 2; ++ct) {
          s16x8 bf = *(const s16x8*)(Bw + (ct * 16 + l15) * DD + kc * 64 + ks * 32 + quad * 8);
          acc[ct] = __builtin_amdgcn_mfma_f32_16x16x32_bf16(af, bf, acc[ct], 0, 0, 0);
        }
      }
    }
    // epilogue: bias + mask, park tile in LDS + global outs
#pragma unroll
    for (int ct = 0; ct < 2; ++ct) {
      int n = ct * 16 + l15;
      if (n < NL) {
        float b = sb[n];
#pragma unroll
        for (int r = 0; r < 4; ++r) {
          int lr = quad * 4 + r;
          int row = r0 + lr;
          float v = acc[ct][r] + b;
          if (n == IDX_EOS && msk[row] == 0.f) v += 20000.f;
          osh[lr * NL + n] = v;
          outs[(size_t)row * NL + n] = v;
        }
      }
    }
  }
  __syncthreads();

  // tgt-energy partial for this block's 16 rows (clean-tree offs 8,4,2,1)
  if (tid < 16) {
    int r = r0 + tid;
    int tg = target[r];
    int prv = ((r & (TT - 1)) == 0) ? IDX_BOS : target[r - 1];
    float cc = tr[prv * NL + tg] + osh[tid * NL + tg];
#pragma unroll
    for (int off = 8; off; off >>= 1) cc += __shfl_down(cc, off);
    if (tid == 0) ws_partial[blockIdx.x] = cc;
  }

  // energy: 16*961 = 15376 f32 = 3844 vec4 (base 16B-aligned)
  float* dst = energy + (size_t)r0 * 961;
#pragma unroll 5
  for (int it = 0; it < 15; ++it) {
    int v = it * 256 + tid;
    int e = v * 4;
    f32x4 val;
#pragma unroll
    for (int k = 0; k < 4; ++k) {
      unsigned x = e + k;
      unsigned q = __umulhi(x, 4469269u);        // x / 961 (exact, x < 20M)
      unsigned c = x - q * 961u;
      unsigned j = c - 31u * ((c * 67651u) >> 21); // c % 31 (exact, c < 961)
      val[k] = tr[c] + osh[q * NL + j];
    }
    *(f32x4*)(dst + e) = val;
  }
  if (tid < 4) {
    int e = (3840 + tid) * 4;
    f32x4 val;
#pragma unroll
    for (int k = 0; k < 4; ++k) {
      unsigned x = e + k;
      unsigned q = __umulhi(x, 4469269u);
      unsigned c = x - q * 961u;
      unsigned j = c - 31u * ((c * 67651u) >> 21);
      val[k] = tr[c] + osh[q * NL + j];
    }
    *(f32x4*)(dst + e) = val;
  }
}

// ------------- K2 fused: 8-step seg matrices + in-block quad product --------
// 4 waves/block = 4 consecutive same-batch units; quad product M3*M2*M1*M0
// done in-LDS, so Mseg16 never touches global memory.
__global__ __launch_bounds__(256) void k_seg(
    const float* __restrict__ outs, const float* __restrict__ trans,
    unsigned short* __restrict__ Mq16, float* __restrict__ Sq)
{
  __shared__ float ub4[4][256];
  __shared__ __align__(16) unsigned short Ms[4][1024];
  __shared__ float Ss[4];
  int tid = threadIdx.x, wave = tid >> 6, lane = tid & 63;
  int l = lane & 31, h = lane >> 5;
  int unit = blockIdx.x * 4 + wave;
  int b = unit >> 6, c = unit & 63;
  int t0 = 1 + c * 8;
  int n = (c == 63) ? 7 : 8;

  float* ub = ub4[wave];
#pragma unroll
  for (int it = 0; it < 4; ++it) {
    int idx = lane + it * 64;
    int row = idx >> 5, col = idx & 31;
    float v = 0.f;
    if (col < NL && row < n)
      v = exp2f(LOG2E * outs[((size_t)b * TT + t0 + row) * NL + col]);
    ub[idx] = v;
  }

  Frag8 A1, A2, B1, B2;
#pragma unroll
  for (int m = 0; m < 4; ++m) {
    int k0 = 8 * h + 2 * m, k1 = k0 + 1;
    float a0 = (k0 < NL && l < NL) ? exp2f(LOG2E * trans[k0 * NL + l]) : 0.f;
    float a1 = (k1 < NL && l < NL) ? exp2f(LOG2E * trans[k1 * NL + l]) : 0.f;
    A1.u[m] = pk2(a0, a1);
    int k2 = 16 + k0, k3 = 16 + k1;
    float a2 = (k2 < NL && l < NL) ? exp2f(LOG2E * trans[k2 * NL + l]) : 0.f;
    float a3 = (k3 < NL && l < NL) ? exp2f(LOG2E * trans[k3 * NL + l]) : 0.f;
    A2.u[m] = pk2(a2, a3);
    B1.u[m] = ((k0 == l) ? 0x3f80u : 0u) | (((k1 == l) ? 0x3f80u : 0u) << 16);
    B2.u[m] = ((k2 == l) ? 0x3f80u : 0u) | (((k3 == l) ? 0x3f80u : 0u) << 16);
  }

  float E[16];
  for (int s = 0; s < n; ++s) {
    const float* us = ub + s * 32 + 4 * h;
    f32x4 u0 = *(const f32x4*)(us);
    f32x4 u1 = *(const f32x4*)(us + 8);
    f32x4 u2 = *(const f32x4*)(us + 16);
    f32x4 u3 = *(const f32x4*)(us + 24);
    f32x16 D = {};
    D = __builtin_amdgcn_mfma_f32_32x32x16_bf16(A1.s, B1.s, D, 0, 0, 0);
    D = __builtin_amdgcn_mfma_f32_32x32x16_bf16(A2.s, B2.s, D, 0, 0, 0);
#pragma unroll
    for (int jj = 0; jj < 4; ++jj) {
      E[jj]      = D[jj]      * u0[jj];
      E[4 + jj]  = D[4 + jj]  * u1[jj];
      E[8 + jj]  = D[8 + jj]  * u2[jj];
      E[12 + jj] = D[12 + jj] * u3[jj];
    }
    if (s + 1 < n) repack(E, h, B1, B2);
  }
  float S = 0.f;
  renorm16(E, S);
  unsigned short* mo = Ms[wave];
#pragma unroll
  for (int r = 0; r < 16; ++r) {
    int row = (r & 3) + 8 * (r >> 2) + 4 * h;
    mo[row * 32 + l] = bf16r(E[r]);
  }
  if (lane == 0) Ss[wave] = S;
  __syncthreads();

  if (wave == 0) {
    // quad product Q = M3*M2*M1*M0, one wave, in LDS
    load_B16(Ms[0], l, h, B1, B2);
    float Sx = Ss[0] + Ss[1] + Ss[2] + Ss[3];
    float E2[16];
#pragma unroll
    for (int i = 1; i < 4; ++i) {
      load_A16(Ms[i], l, h, A1, A2);
      f32x16 D = {};
      D = __builtin_amdgcn_mfma_f32_32x32x16_bf16(A1.s, B1.s, D, 0, 0, 0);
      D = __builtin_amdgcn_mfma_f32_32x32x16_bf16(A2.s, B2.s, D, 0, 0, 0);
#pragma unroll
      for (int r = 0; r < 16; ++r) E2[r] = D[r];
      if (i < 3) repack(E2, h, B1, B2);
    }
    renorm16(E2, Sx);
    unsigned short* qo = Mq16 + (size_t)blockIdx.x * 1024;
#pragma unroll
    for (int r = 0; r < 16; ++r) {
      int row = (r & 3) + 8 * (r >> 2) + 4 * h;
      qo[row * 32 + l] = bf16r(E2[r]);
    }
    if (lane == 0) Sq[blockIdx.x] = Sx;
  }
}

// ------------- K3: per-batch final product + lse + loss ---------------------
__global__ __launch_bounds__(256) void k_tree2(
    const float* __restrict__ outs, const float* __restrict__ trans,
    const unsigned short* __restrict__ Mq16, const float* __restrict__ Sq,
    const float* __restrict__ ws_partial, float* __restrict__ loss)
{
  int tid = threadIdx.x, wave = tid >> 6, lane = tid & 63;
  int l = lane & 31, h = lane >> 5;
  int b = blockIdx.x * 4 + wave;
  const unsigned short* base = Mq16 + (size_t)b * 16384;
  Frag8 A1, A2, B1, B2;
  load_B16(base, l, h, B1, B2);
  float S = 0.f;
#pragma unroll
  for (int q = 0; q < 16; ++q) S += Sq[b * 16 + q];
  float E[16];
  for (int i = 1; i < 16; ++i) {
    load_A16(base + i * 1024, l, h, A1, A2);
    f32x16 D = {};
    D = __builtin_amdgcn_mfma_f32_32x32x16_bf16(A1.s, B1.s, D, 0, 0, 0);
    D = __builtin_amdgcn_mfma_f32_32x32x16_bf16(A2.s, B2.s, D, 0, 0, 0);
#pragma unroll
    for (int r = 0; r < 16; ++r) E[r] = D[r];
    if ((i & 3) == 3) renorm16(E, S);
    if (i < 15) repack(E, h, B1, B2);
  }
  float p0 = (l < NL) ? exp2f(LOG2E * (trans[IDX_BOS * NL + l] + outs[(size_t)b * TT * NL + l])) : 0.f;
  float sum_h = 0.f;
#pragma unroll
  for (int r = 0; r < 16; ++r) {
    float s = bfly_sum32(E[r] * p0);
    int row = (r & 3) + 8 * (r >> 2) + 4 * h;
    float We = (row < NL) ? exp2f(LOG2E * trans[row * NL + IDX_EOS]) : 0.f;
    sum_h += s * We;
  }
  float tot = sum_h + __shfl_xor(sum_h, 32);
  if (lane == 0) {
    float wst = 0.f;
#pragma unroll
    for (int i = 0; i < 32; ++i) wst += ws_partial[b * 32 + i];
    loss[b] = LN2F * (S + log2f(tot)) - wst;
  }
}

extern "C" void kernel_launch(void* const* d_in, const int* in_sizes, int n_in,
                              void* d_out, int out_size, void* d_ws, size_t ws_size,
                              hipStream_t stream) {
  const float* inp   = (const float*)d_in[0];   // (64,512,768) f32
  const int*   tgt   = (const int*)d_in[1];     // (64,512) int
  const float* msk   = (const float*)d_in[2];   // (64,512) f32
  const float* sw    = (const float*)d_in[3];   // (31,768) f32
  const float* sb    = (const float*)d_in[4];   // (31,) f32
  const float* trans = (const float*)d_in[5];   // (31,31) f32

  float* out    = (float*)d_out;
  float* loss   = out;
  float* energy = out + BB;

  // d_ws layout (~6.2 MB used)
  float* outs        = (float*)d_ws;                        // 32768*31 f32
  float* Sq          = outs + (size_t)RTOT * NL;            // 1024
  float* ws_partial  = Sq + 1024;                           // 2048
  unsigned short* Mq16 = (unsigned short*)(ws_partial + 2048); // 1024*1024 bf16
  unsigned short* Bw   = Mq16 + (size_t)1024 * 1024;          // 32*768 bf16

  k_prep<<<8, 256, 0, stream>>>(sw, Bw);
  k_outs<<<RTOT / 16, 256, 0, stream>>>(inp, Bw, sb, msk, trans, tgt, outs, energy, ws_partial);
  k_seg<<<1024, 256, 0, stream>>>(outs, trans, Mq16, Sq);
  k_tree2<<<16, 256, 0, stream>>>(outs, trans, Mq16, Sq, ws_partial, loss);
}

// Round 4
// 264.202 us; speedup vs baseline: 1.8970x; 1.1791x over previous
//
#include <hip/hip_runtime.h>

typedef float f32x4  __attribute__((ext_vector_type(4)));
typedef float f32x16 __attribute__((ext_vector_type(16)));
typedef short s16x8  __attribute__((ext_vector_type(8)));

constexpr int NL  = 31;
constexpr int BB  = 64;
constexpr int TT  = 512;
constexpr int DD  = 768;
constexpr int RTOT = BB * TT;
constexpr int IDX_EOS = 29;
constexpr int IDX_BOS = 30;
constexpr float LOG2E = 1.4426950408889634f;
constexpr float LN2F  = 0.6931471805599453f;

union Frag8 { unsigned u[4]; s16x8 s; };

__device__ inline unsigned pk2(float a, float b) {
  unsigned ua = __float_as_uint(a), ub = __float_as_uint(b);
  ua = (ua + 0x7fffu + ((ua >> 16) & 1u)) >> 16;   // RNE f32->bf16
  ub = (ub + 0x7fffu + ((ub >> 16) & 1u)) >> 16;
  return ua | (ub << 16);
}
__device__ inline unsigned short bf16r(float a) {
  unsigned ua = __float_as_uint(a);
  return (unsigned short)((ua + 0x7fffu + ((ua >> 16) & 1u)) >> 16);
}

__device__ inline float bfly_max32(float v) {
#define STEPM(K) { float o = __int_as_float(__builtin_amdgcn_ds_swizzle(__float_as_int(v), ((K) << 10) | 0x1f)); v = fmaxf(v, o); }
  STEPM(1) STEPM(2) STEPM(4) STEPM(8) STEPM(16)
#undef STEPM
  return v;
}
__device__ inline float bfly_sum32(float v) {
#define STEPS(K) { float o = __int_as_float(__builtin_amdgcn_ds_swizzle(__float_as_int(v), ((K) << 10) | 0x1f)); v = v + o; }
  STEPS(1) STEPS(2) STEPS(4) STEPS(8) STEPS(16)
#undef STEPS
  return v;
}

// D(C-layout, f32[16]) -> B-frag(bf16) half-swap repack [R2-verified]
__device__ inline void repack(const float E[16], int h, Frag8& B1, Frag8& B2) {
  unsigned o1a = pk2(E[4 * h], E[4 * h + 1]), o1b = pk2(E[4 * h + 2], E[4 * h + 3]);
  unsigned o2a = pk2(E[8 + 4 * h], E[8 + 4 * h + 1]), o2b = pk2(E[8 + 4 * h + 2], E[8 + 4 * h + 3]);
  int hb = 4 * (1 - h);
  unsigned s1a = pk2(E[hb], E[hb + 1]),         s1b = pk2(E[hb + 2], E[hb + 3]);
  unsigned s2a = pk2(E[8 + hb], E[8 + hb + 1]), s2b = pk2(E[8 + hb + 2], E[8 + hb + 3]);
  unsigned r1a = __shfl_xor((int)s1a, 32), r1b = __shfl_xor((int)s1b, 32);
  unsigned r2a = __shfl_xor((int)s2a, 32), r2b = __shfl_xor((int)s2b, 32);
  if (h == 0) {
    B1.u[0] = o1a; B1.u[1] = o1b; B1.u[2] = r1a; B1.u[3] = r1b;
    B2.u[0] = o2a; B2.u[1] = o2b; B2.u[2] = r2a; B2.u[3] = r2b;
  } else {
    B1.u[0] = r1a; B1.u[1] = r1b; B1.u[2] = o1a; B1.u[3] = o1b;
    B2.u[0] = r2a; B2.u[1] = r2b; B2.u[2] = o2a; B2.u[3] = o2b;
  }
}

__device__ inline void renorm16(float E[16], float& Sacc) {
  float m = E[0];
#pragma unroll
  for (int r = 1; r < 16; ++r) m = fmaxf(m, E[r]);
  m = bfly_max32(m);
  m = fmaxf(m, __shfl_xor(m, 32));
  float lg = truncf(log2f(m));
  Sacc += lg;
  float sc = exp2f(-lg);
#pragma unroll
  for (int r = 0; r < 16; ++r) E[r] *= sc;
}

// bf16 row-major 32x32 matrix -> A-frags (A[m][k], m = lane&31)
__device__ inline void load_A16(const unsigned short* M, int l, int h, Frag8& A1, Frag8& A2) {
  A1.s = *(const s16x8*)(M + l * 32 + 8 * h);
  A2.s = *(const s16x8*)(M + l * 32 + 16 + 8 * h);
}
// bf16 row-major 32x32 matrix -> B-frags (B[k][n], n = lane&31)
__device__ inline void load_B16(const unsigned short* M, int l, int h, Frag8& B1, Frag8& B2) {
#pragma unroll
  for (int m = 0; m < 4; ++m) {
    int k = 8 * h + 2 * m;
    unsigned lo0 = M[k * 32 + l],        hi0 = M[(k + 1) * 32 + l];
    unsigned lo1 = M[(k + 16) * 32 + l], hi1 = M[(k + 17) * 32 + l];
    B1.u[m] = lo0 | (hi0 << 16);
    B2.u[m] = lo1 | (hi1 << 16);
  }
}

// LDS tree node: result = T[ja] * T[jb] -> stored at T[jb] (bf16), Ts[jb] += S
// (ja = LATER segment, jb = EARLIER segment)  [R2-verified]
__device__ inline void tree_node(unsigned short* Tb, float* Ts, int ja, int jb, int l, int h) {
  Frag8 A1, A2, B1, B2;
  load_A16(Tb + ja * 1024, l, h, A1, A2);
  load_B16(Tb + jb * 1024, l, h, B1, B2);
  f32x16 D = {};
  D = __builtin_amdgcn_mfma_f32_32x32x16_bf16(A1.s, B1.s, D, 0, 0, 0);
  D = __builtin_amdgcn_mfma_f32_32x32x16_bf16(A2.s, B2.s, D, 0, 0, 0);
  float E[16];
#pragma unroll
  for (int r = 0; r < 16; ++r) E[r] = D[r];
  float S = Ts[ja] + Ts[jb];
  renorm16(E, S);
#pragma unroll
  for (int r = 0; r < 16; ++r) {
    int row = (r & 3) + 8 * (r >> 2) + 4 * h;
    Tb[jb * 1024 + row * 32 + l] = bf16r(E[r]);
  }
  if (l == 0 && h == 0) Ts[jb] = S;
}

// ------------- K0: state_w -> bf16 padded ----------------------------------
__global__ void k_prep(const float* __restrict__ sw, unsigned short* __restrict__ Bw) {
  for (int i = blockIdx.x * 256 + threadIdx.x; i < 32 * DD; i += 8 * 256)
    Bw[i] = (i < NL * DD) ? bf16r(sw[i]) : (unsigned short)0;
}

// ------------- K1 fused: GEMM + energy + tgt partial + seg sub-products -----
// 2048 blocks x 16 rows. Wave 0: direct-load GEMM (no LDS staging); waves 1-3
// preload trans. Then all waves: energy stream; then each wave builds the
// 4-step CRF sub-product for its rows from osh (block k=0 starts at t=1);
// wave 0 combines the 4 sub-products -> one segment matrix per block (Mb).
__global__ __launch_bounds__(256) void k_fused(
    const float* __restrict__ inp, const unsigned short* __restrict__ Bw,
    const float* __restrict__ sb, const float* __restrict__ msk,
    const float* __restrict__ trans, const int* __restrict__ target,
    float* __restrict__ energy, float* __restrict__ ws_partial,
    unsigned short* __restrict__ Mb, float* __restrict__ Sb,
    float* __restrict__ out0)
{
  __shared__ float tr[961];
  __shared__ float osh[16 * NL];
  __shared__ float ubw[4][128];
  __shared__ __align__(16) unsigned short Ms[4][1024];
  __shared__ float Ss[4];
  int tid = threadIdx.x, wave = tid >> 6, lane = tid & 63;
  int bid = blockIdx.x;
  int r0 = bid * 16;

  if (wave) {
    // waves 1-3: trans -> LDS while wave 0 runs the GEMM
    for (int idx = tid - 64; idx < 961; idx += 192) tr[idx] = trans[idx];
  } else {
    // ---- wave 0: 16-row GEMM, direct per-lane A-fragment loads ----
    int quad = lane >> 4, l15 = lane & 15;
    const float* arow = inp + (size_t)(r0 + l15) * DD + quad * 8;

    f32x4 pa0a = *(const f32x4*)(arow);
    f32x4 pa0b = *(const f32x4*)(arow + 4);
    f32x4 pa1a = *(const f32x4*)(arow + 32);
    f32x4 pa1b = *(const f32x4*)(arow + 36);

    f32x4 acc[2] = {};
    for (int kc = 0; kc < 12; ++kc) {
      Frag8 af0, af1;
      af0.u[0] = pk2(pa0a[0], pa0a[1]); af0.u[1] = pk2(pa0a[2], pa0a[3]);
      af0.u[2] = pk2(pa0b[0], pa0b[1]); af0.u[3] = pk2(pa0b[2], pa0b[3]);
      af1.u[0] = pk2(pa1a[0], pa1a[1]); af1.u[1] = pk2(pa1a[2], pa1a[3]);
      af1.u[2] = pk2(pa1b[0], pa1b[1]); af1.u[3] = pk2(pa1b[2], pa1b[3]);
      if (kc < 11) {
        const float* a2 = arow + (kc + 1) * 64;
        pa0a = *(const f32x4*)(a2);      pa0b = *(const f32x4*)(a2 + 4);
        pa1a = *(const f32x4*)(a2 + 32); pa1b = *(const f32x4*)(a2 + 36);
      }
#pragma unroll
      for (int ct = 0; ct < 2; ++ct) {
        s16x8 bf0 = *(const s16x8*)(Bw + (ct * 16 + l15) * DD + kc * 64 + quad * 8);
        acc[ct] = __builtin_amdgcn_mfma_f32_16x16x32_bf16(af0.s, bf0, acc[ct], 0, 0, 0);
        s16x8 bf1 = *(const s16x8*)(Bw + (ct * 16 + l15) * DD + kc * 64 + 32 + quad * 8);
        acc[ct] = __builtin_amdgcn_mfma_f32_16x16x32_bf16(af1.s, bf1, acc[ct], 0, 0, 0);
      }
    }
    // epilogue: bias + mask -> osh
#pragma unroll
    for (int ct = 0; ct < 2; ++ct) {
      int n = ct * 16 + l15;
      if (n < NL) {
        float b = sb[n];
#pragma unroll
        for (int r = 0; r < 4; ++r) {
          int lr = quad * 4 + r;
          float v = acc[ct][r] + b;
          if (n == IDX_EOS && msk[r0 + lr] == 0.f) v += 20000.f;
          osh[lr * NL + n] = v;
        }
      }
    }
  }
  __syncthreads();

  // batch-first block (k==0): save row 0 of outs for the final p0
  if ((bid & 31) == 0 && tid < NL) out0[(bid >> 5) * NL + tid] = osh[tid];

  // tgt-energy partial for this block's 16 rows
  if (tid < 16) {
    int r = r0 + tid;
    int tg = target[r];
    int prv = ((r & (TT - 1)) == 0) ? IDX_BOS : target[r - 1];
    float cc = tr[prv * NL + tg] + osh[tid * NL + tg];
#pragma unroll
    for (int off = 8; off; off >>= 1) cc += __shfl_down(cc, off);
    if (tid == 0) ws_partial[bid] = cc;
  }

  // ---- energy stream: 16*961 = 15376 f32 = 3844 vec4 (base 16B-aligned) ----
  float* dst = energy + (size_t)r0 * 961;
#pragma unroll 5
  for (int it = 0; it < 15; ++it) {
    int v = it * 256 + tid;
    int e = v * 4;
    f32x4 val;
#pragma unroll
    for (int k = 0; k < 4; ++k) {
      unsigned x = e + k;
      unsigned q = __umulhi(x, 4469269u);        // x / 961 (exact, x < 20M)
      unsigned c = x - q * 961u;
      unsigned j = c - 31u * ((c * 67651u) >> 21); // c % 31 (exact, c < 961)
      val[k] = tr[c] + osh[q * NL + j];
    }
    *(f32x4*)(dst + e) = val;
  }
  if (tid < 4) {
    int e = (3840 + tid) * 4;
    f32x4 val;
#pragma unroll
    for (int k = 0; k < 4; ++k) {
      unsigned x = e + k;
      unsigned q = __umulhi(x, 4469269u);
      unsigned c = x - q * 961u;
      unsigned j = c - 31u * ((c * 67651u) >> 21);
      val[k] = tr[c] + osh[q * NL + j];
    }
    *(f32x4*)(dst + e) = val;
  }

  // ---- seg sub-product: wave w covers steps t = r0 + 4w .. r0+4w+3 ----
  {
    int l = lane & 31, h = lane >> 5;
    int s0 = (bid % 32 == 0 && wave == 0) ? 1 : 0;   // t=0 is not a step

    float* ub = ubw[wave];
#pragma unroll
    for (int it = 0; it < 2; ++it) {
      int idx = lane + it * 64;
      int row = idx >> 5, col = idx & 31;
      float v = 0.f;
      if (col < NL) v = exp2f(LOG2E * osh[(4 * wave + row) * NL + col]);
      ub[idx] = v;
    }

    Frag8 A1, A2, B1, B2;
#pragma unroll
    for (int m = 0; m < 4; ++m) {
      int k0 = 8 * h + 2 * m, k1 = k0 + 1;
      float a0 = (k0 < NL && l < NL) ? exp2f(LOG2E * tr[k0 * NL + l]) : 0.f;
      float a1 = (k1 < NL && l < NL) ? exp2f(LOG2E * tr[k1 * NL + l]) : 0.f;
      A1.u[m] = pk2(a0, a1);
      int k2 = 16 + k0, k3 = 16 + k1;
      float a2 = (k2 < NL && l < NL) ? exp2f(LOG2E * tr[k2 * NL + l]) : 0.f;
      float a3 = (k3 < NL && l < NL) ? exp2f(LOG2E * tr[k3 * NL + l]) : 0.f;
      A2.u[m] = pk2(a2, a3);
      B1.u[m] = ((k0 == l) ? 0x3f80u : 0u) | (((k1 == l) ? 0x3f80u : 0u) << 16);
      B2.u[m] = ((k2 == l) ? 0x3f80u : 0u) | (((k3 == l) ? 0x3f80u : 0u) << 16);
    }

    float E[16];
    for (int s = s0; s < 4; ++s) {
      const float* us = ub + s * 32 + 4 * h;
      f32x4 u0 = *(const f32x4*)(us);
      f32x4 u1 = *(const f32x4*)(us + 8);
      f32x4 u2 = *(const f32x4*)(us + 16);
      f32x4 u3 = *(const f32x4*)(us + 24);
      f32x16 D = {};
      D = __builtin_amdgcn_mfma_f32_32x32x16_bf16(A1.s, B1.s, D, 0, 0, 0);
      D = __builtin_amdgcn_mfma_f32_32x32x16_bf16(A2.s, B2.s, D, 0, 0, 0);
#pragma unroll
      for (int jj = 0; jj < 4; ++jj) {
        E[jj]      = D[jj]      * u0[jj];
        E[4 + jj]  = D[4 + jj]  * u1[jj];
        E[8 + jj]  = D[8 + jj]  * u2[jj];
        E[12 + jj] = D[12 + jj] * u3[jj];
      }
      if (s < 3) repack(E, h, B1, B2);
    }
    float S = 0.f;
    renorm16(E, S);
    unsigned short* mo = Ms[wave];
#pragma unroll
    for (int r = 0; r < 16; ++r) {
      int row = (r & 3) + 8 * (r >> 2) + 4 * h;
      mo[row * 32 + l] = bf16r(E[r]);
    }
    if (lane == 0) Ss[wave] = S;
  }
  __syncthreads();

  if (wave == 0) {
    // combine: block segment = P3*P2*P1*P0 (wave 0 earliest)
    int l = lane & 31, h = lane >> 5;
    Frag8 A1, A2, B1, B2;
    load_B16(Ms[0], l, h, B1, B2);
    float Sx = Ss[0] + Ss[1] + Ss[2] + Ss[3];
    float E2[16];
#pragma unroll
    for (int i = 1; i < 4; ++i) {
      load_A16(Ms[i], l, h, A1, A2);
      f32x16 D = {};
      D = __builtin_amdgcn_mfma_f32_32x32x16_bf16(A1.s, B1.s, D, 0, 0, 0);
      D = __builtin_amdgcn_mfma_f32_32x32x16_bf16(A2.s, B2.s, D, 0, 0, 0);
#pragma unroll
      for (int r = 0; r < 16; ++r) E2[r] = D[r];
      if (i < 3) repack(E2, h, B1, B2);
    }
    renorm16(E2, Sx);
    unsigned short* qo = Mb + (size_t)bid * 1024;
#pragma unroll
    for (int r = 0; r < 16; ++r) {
      int row = (r & 3) + 8 * (r >> 2) + 4 * h;
      qo[row * 32 + l] = bf16r(E2[r]);
    }
    if (lane == 0) Sb[bid] = Sx;
  }
}

// ------------- K2: per-batch depth-5 tree over 32 segment matrices + loss ---
__global__ __launch_bounds__(256) void k_tree(
    const float* __restrict__ trans, const unsigned short* __restrict__ Mb,
    const float* __restrict__ Sb, const float* __restrict__ ws_partial,
    const float* __restrict__ out0, float* __restrict__ loss)
{
  __shared__ __align__(16) unsigned short T[32][1024];
  __shared__ float Ts[32];
  __shared__ float wsh[32];
  int tid = threadIdx.x, wave = tid >> 6, lane = tid & 63;
  int l = lane & 31, h = lane >> 5;
  int b = blockIdx.x;

  const f32x4* src = (const f32x4*)(Mb + (size_t)b * 32 * 1024);
  f32x4* dstT = (f32x4*)T;
#pragma unroll
  for (int i = 0; i < 16; ++i) dstT[tid + i * 256] = src[tid + i * 256];
  if (tid < 32) {
    Ts[tid] = Sb[b * 32 + tid];
    wsh[tid] = ws_partial[b * 32 + tid];
  }
  __syncthreads();

  unsigned short* T0 = T[0];
  // L1 (32->16): node(2j+1, 2j)
#pragma unroll
  for (int i = 0; i < 4; ++i) { int j = wave + 4 * i; tree_node(T0, Ts, 2 * j + 1, 2 * j, l, h); }
  __syncthreads();
  // L2 (16->8): node(4j+2, 4j)
#pragma unroll
  for (int i = 0; i < 2; ++i) { int j = wave + 4 * i; tree_node(T0, Ts, 4 * j + 2, 4 * j, l, h); }
  __syncthreads();
  // L3 (8->4): node(8j+4, 8j)
  { int j = wave; tree_node(T0, Ts, 8 * j + 4, 8 * j, l, h); }
  __syncthreads();
  // L4 (4->2): node(16j+8, 16j)
  if (wave < 2) { int j = wave; tree_node(T0, Ts, 16 * j + 8, 16 * j, l, h); }
  __syncthreads();

  // L5 + finalize (wave 0): full = T[16] * T[0]
  if (wave == 0) {
    Frag8 A1, A2, B1, B2;
    load_A16(T0 + 16 * 1024, l, h, A1, A2);
    load_B16(T0, l, h, B1, B2);
    f32x16 D = {};
    D = __builtin_amdgcn_mfma_f32_32x32x16_bf16(A1.s, B1.s, D, 0, 0, 0);
    D = __builtin_amdgcn_mfma_f32_32x32x16_bf16(A2.s, B2.s, D, 0, 0, 0);
    float E[16];
#pragma unroll
    for (int r = 0; r < 16; ++r) E[r] = D[r];
    float S = Ts[0] + Ts[16];

    float p0 = (l < NL) ? exp2f(LOG2E * (trans[IDX_BOS * NL + l] + out0[b * NL + l])) : 0.f;
    float sum_h = 0.f;
#pragma unroll
    for (int r = 0; r < 16; ++r) {
      float s = bfly_sum32(E[r] * p0);
      int row = (r & 3) + 8 * (r >> 2) + 4 * h;
      float We = (row < NL) ? exp2f(LOG2E * trans[row * NL + IDX_EOS]) : 0.f;
      sum_h += s * We;
    }
    float tot = sum_h + __shfl_xor(sum_h, 32);
    if (lane == 0) {
      float wst = 0.f;
#pragma unroll
      for (int i = 0; i < 32; ++i) wst += wsh[i];
      loss[b] = LN2F * (S + log2f(tot)) - wst;
    }
  }
}

extern "C" void kernel_launch(void* const* d_in, const int* in_sizes, int n_in,
                              void* d_out, int out_size, void* d_ws, size_t ws_size,
                              hipStream_t stream) {
  const float* inp   = (const float*)d_in[0];   // (64,512,768) f32
  const int*   tgt   = (const int*)d_in[1];     // (64,512) int
  const float* msk   = (const float*)d_in[2];   // (64,512) f32
  const float* sw    = (const float*)d_in[3];   // (31,768) f32
  const float* sb    = (const float*)d_in[4];   // (31,) f32
  const float* trans = (const float*)d_in[5];   // (31,31) f32

  float* out    = (float*)d_out;
  float* loss   = out;
  float* energy = out + BB;

  // d_ws layout (~4.1 MB used)
  float* ws_partial = (float*)d_ws;                    // 2048
  float* Sb   = ws_partial + 2048;                     // 2048
  float* out0 = Sb + 2048;                             // 64*31 -> pad 2048
  unsigned short* Mb = (unsigned short*)(out0 + 2048); // 2048*1024 bf16
  unsigned short* Bw = Mb + (size_t)2048 * 1024;       // 32*768 bf16

  k_prep<<<8, 256, 0, stream>>>(sw, Bw);
  k_fused<<<RTOT / 16, 256, 0, stream>>>(inp, Bw, sb, msk, trans, tgt,
                                         energy, ws_partial, Mb, Sb, out0);
  k_tree<<<BB, 256, 0, stream>>>(trans, Mb, Sb, ws_partial, out0, loss);
}